// Round 14
// baseline (157.949 us; speedup 1.0000x reference)
//
#include <hip/hip_runtime.h>

// CrossAttention with LoRA (folded). B=16, C=64, hw=4096, L=77, COND=768, HEADS=8, dh=8.
// Round 15: megattn LDS-pipe fix. Per-CU pipe accounting of r6 showed the LDS pipe at
// ~97% (staging writes 59K cyc + attn reads 30K + ao 27K of 120K total) — THE saturated
// resource (explains VALUBusy pinned at 44% across all geometries, r13 regression).
// Fix: DELETE K/V LDS staging; attention reads kbuf/vbuf direct from global (39.4KB/block,
// L1/L2-resident, each element read once, VMEM pipe was idle). 2 of 3 barriers gone.
// LDS now only the ao[128][65] round-trip. Q/ao/O phases + prep/kvproj5 byte-identical r6.
// Pipeline: prep_weights -> kvproj5 -> megattn  (3 launches).

#define HW   4096
#define CHN  64
#define LSEQ 77
#define CD   768
#define NB   16

// workspace float offsets
#define OFF_WQ 0
#define OFF_WK 4096
#define OFF_WV 53248
#define OFF_WO 102400
#define OFF_K  106496
#define OFF_V  185344

#define QF 0.51011784563163f  // SCALE * log2(e) = 8^-0.5 * 1.442695...

__global__ __launch_bounds__(256) void prep_weights(
    const float* __restrict__ Wq, const float* __restrict__ Aq, const float* __restrict__ Bq,
    const float* __restrict__ Wk, const float* __restrict__ Ak, const float* __restrict__ Bk,
    const float* __restrict__ Wv, const float* __restrict__ Av, const float* __restrict__ Bv,
    const float* __restrict__ Wo, const float* __restrict__ Ao, const float* __restrict__ Bo,
    float* __restrict__ ws) {
  int idx = blockIdx.x * 256 + threadIdx.x;   // 416*256 = 106496 exact
  const float *W, *A, *Bm;
  float* out;
  int in_d, local;
  float scale = 1.0f;
  if (idx < 4096)        { W = Wq; A = Aq; Bm = Bq; out = ws + OFF_WQ; in_d = 64;  local = idx; scale = QF; }
  else if (idx < 53248)  { W = Wk; A = Ak; Bm = Bk; out = ws + OFF_WK; in_d = 768; local = idx - 4096; }
  else if (idx < 102400) { W = Wv; A = Av; Bm = Bv; out = ws + OFF_WV; in_d = 768; local = idx - 53248; }
  else                   { W = Wo; A = Ao; Bm = Bo; out = ws + OFF_WO; in_d = 64;  local = idx - 102400; }
  int co = local & 63;
  int c  = local >> 6;
  float val = W[co * in_d + c];
  #pragma unroll
  for (int r = 0; r < 8; r++) val += Bm[co * 8 + r] * A[r * in_d + c];
  out[local] = val * scale;   // local == c*64+co : W_eff^T [in][out]
}

// K/V projection (verified r6): grid (308, 2 kv), block 256 = 4 waves.
// Wave q owns K-quarter; lane l: l16=l&15 (co quad), cs=l>>4. Weight fetch float4:
// wave = 1KB contiguous; x reads = LDS broadcasts; 16 partial groups -> LDS reduce.
__global__ __launch_bounds__(256) void kvproj5(
    const float* __restrict__ cond,  // [1232][768]
    const float* __restrict__ wkT,   // [768][64]
    const float* __restrict__ wvT,
    const float* __restrict__ bk, const float* __restrict__ bv,
    float* __restrict__ kbuf,        // [1232][64]
    float* __restrict__ vbuf) {
  __shared__ float xs[4 * CD];       // 12KB: x[4 rows][768]
  __shared__ float red[16 * 256];    // 16KB: [group][row][co]
  int kv = blockIdx.y;
  int r0 = blockIdx.x * 4;           // 308*4 = 1232 exact
  int t  = threadIdx.x;
  int l  = t & 63;
  int q  = __builtin_amdgcn_readfirstlane(t >> 6);   // wave id = K-quarter
  int l16 = l & 15;
  int cs  = l >> 4;                  // c-phase within quarter

  {
    const float4* src = (const float4*)(cond + r0 * CD);
    float4* dst = (float4*)xs;
    #pragma unroll
    for (int i = 0; i < 3; i++) dst[t + 256 * i] = src[t + 256 * i];  // 768 float4 exact
  }
  __syncthreads();

  const float4* wT4 = (const float4*)(kv ? wvT : wkT);   // [768*16] float4
  float4 a0 = make_float4(0.f, 0.f, 0.f, 0.f);
  float4 a1 = a0, a2 = a0, a3 = a0;
  int cbase = q * 192 + cs;
  #pragma unroll 8
  for (int it = 0; it < 48; it++) {
    int c = cbase + 4 * it;
    float4 w  = wT4[c * 16 + l16];       // wave: 64 consecutive float4 = 1KB
    float x0 = xs[0 * CD + c];           // 4 distinct addrs, 16-lane broadcast each
    float x1 = xs[1 * CD + c];
    float x2 = xs[2 * CD + c];
    float x3 = xs[3 * CD + c];
    a0.x = fmaf(x0, w.x, a0.x); a0.y = fmaf(x0, w.y, a0.y);
    a0.z = fmaf(x0, w.z, a0.z); a0.w = fmaf(x0, w.w, a0.w);
    a1.x = fmaf(x1, w.x, a1.x); a1.y = fmaf(x1, w.y, a1.y);
    a1.z = fmaf(x1, w.z, a1.z); a1.w = fmaf(x1, w.w, a1.w);
    a2.x = fmaf(x2, w.x, a2.x); a2.y = fmaf(x2, w.y, a2.y);
    a2.z = fmaf(x2, w.z, a2.z); a2.w = fmaf(x2, w.w, a2.w);
    a3.x = fmaf(x3, w.x, a3.x); a3.y = fmaf(x3, w.y, a3.y);
    a3.z = fmaf(x3, w.z, a3.z); a3.w = fmaf(x3, w.w, a3.w);
  }

  {
    float4* redq = (float4*)(red + (q * 4 + cs) * 256);
    redq[0 * 16 + l16] = a0;   // row 0
    redq[1 * 16 + l16] = a1;
    redq[2 * 16 + l16] = a2;
    redq[3 * 16 + l16] = a3;
  }
  __syncthreads();

  int r  = t >> 6;                  // 4 rows x 64 co = 256 outputs exact
  int co = t & 63;
  float val = (kv ? bv : bk)[co];
  #pragma unroll
  for (int g = 0; g < 16; g++) val += red[g * 256 + r * 64 + co];
  (kv ? vbuf : kbuf)[(r0 + r) * 64 + co] = val;
}

// Fused q-proj + attention + o-proj. grid (32 ptiles of 128, 16 b), block 256.
// h = t>>5, pl = t&31, 4 px/thread. NO K/V LDS staging: attention reads kbuf/vbuf
// directly (half-wave-uniform addrs -> 2x16B lines per load, L1-resident, each element
// read once per block). LDS = ao[128][65] round-trip only; ONE barrier.
// Logits bounded => single-pass softmax with exp2 (wqT pre-scaled by SCALE*log2e).
__global__ __launch_bounds__(256, 2) void megattn(
    const float* __restrict__ z,     // [16][64][4096]
    const float* __restrict__ wqT,   // [64][64] (pre-scaled by QF)
    const float* __restrict__ bq,
    const float* __restrict__ kbuf,  // [16][77][64]
    const float* __restrict__ vbuf,
    const float* __restrict__ woT,   // [64][64]
    const float* __restrict__ bo,
    float* __restrict__ out) {       // [16][64][4096]
  __shared__ float ao[128 * 65];     // 33.3KB (was 39.4: k|v staging removed)
  int b  = blockIdx.y;
  int p0 = blockIdx.x * 128;
  int t  = threadIdx.x;
  int h  = t >> 5;
  int pl = t & 31;

  // ---- Q phase: q[p][8h..8h+7] for p = p0 + pl + 32*i, i<4 ----
  float qr[4][8];
  {
    const float4 b0 = *(const float4*)(bq + 8 * h);
    const float4 b1 = *(const float4*)(bq + 8 * h + 4);
    #pragma unroll
    for (int i = 0; i < 4; i++) {
      qr[i][0] = b0.x * QF; qr[i][1] = b0.y * QF; qr[i][2] = b0.z * QF; qr[i][3] = b0.w * QF;
      qr[i][4] = b1.x * QF; qr[i][5] = b1.y * QF; qr[i][6] = b1.z * QF; qr[i][7] = b1.w * QF;
    }
  }
  const float* zb = z + b * (CHN * HW) + p0 + pl;
  #pragma unroll 4
  for (int c = 0; c < 64; c++) {
    float4 w0 = *(const float4*)(wqT + c * 64 + 8 * h);
    float4 w1 = *(const float4*)(wqT + c * 64 + 8 * h + 4);
    float zv[4];
    #pragma unroll
    for (int i = 0; i < 4; i++) zv[i] = zb[c * HW + 32 * i];
    #pragma unroll
    for (int i = 0; i < 4; i++) {
      qr[i][0] = fmaf(zv[i], w0.x, qr[i][0]);
      qr[i][1] = fmaf(zv[i], w0.y, qr[i][1]);
      qr[i][2] = fmaf(zv[i], w0.z, qr[i][2]);
      qr[i][3] = fmaf(zv[i], w0.w, qr[i][3]);
      qr[i][4] = fmaf(zv[i], w1.x, qr[i][4]);
      qr[i][5] = fmaf(zv[i], w1.y, qr[i][5]);
      qr[i][6] = fmaf(zv[i], w1.z, qr[i][6]);
      qr[i][7] = fmaf(zv[i], w1.w, qr[i][7]);
    }
  }

  // ---- Attention phase: K/V direct from global (L1/L2-resident, no staging) ----
  const float* kb = kbuf + b * LSEQ * 64 + 8 * h;
  const float* vb = vbuf + b * LSEQ * 64 + 8 * h;
  float acc[4][8];
  float li[4];
  #pragma unroll
  for (int i = 0; i < 4; i++) {
    li[i] = 0.f;
    #pragma unroll
    for (int d = 0; d < 8; d++) acc[i][d] = 0.f;
  }
  #pragma unroll 2
  for (int j = 0; j < LSEQ; j++) {
    float4 k0 = *(const float4*)(kb + j * 64);
    float4 k1 = *(const float4*)(kb + j * 64 + 4);
    float4 v0 = *(const float4*)(vb + j * 64);
    float4 v1 = *(const float4*)(vb + j * 64 + 4);
    #pragma unroll
    for (int i = 0; i < 4; i++) {
      float s = qr[i][0] * k0.x;
      s = fmaf(qr[i][1], k0.y, s);
      s = fmaf(qr[i][2], k0.z, s);
      s = fmaf(qr[i][3], k0.w, s);
      s = fmaf(qr[i][4], k1.x, s);
      s = fmaf(qr[i][5], k1.y, s);
      s = fmaf(qr[i][6], k1.z, s);
      s = fmaf(qr[i][7], k1.w, s);
      float e = __builtin_amdgcn_exp2f(s);
      li[i] += e;
      acc[i][0] = fmaf(e, v0.x, acc[i][0]);
      acc[i][1] = fmaf(e, v0.y, acc[i][1]);
      acc[i][2] = fmaf(e, v0.z, acc[i][2]);
      acc[i][3] = fmaf(e, v0.w, acc[i][3]);
      acc[i][4] = fmaf(e, v1.x, acc[i][4]);
      acc[i][5] = fmaf(e, v1.y, acc[i][5]);
      acc[i][6] = fmaf(e, v1.z, acc[i][6]);
      acc[i][7] = fmaf(e, v1.w, acc[i][7]);
    }
  }

  // ---- ao -> LDS, layout [128][65] (stride 65: 2 lanes/bank = free) ----
  #pragma unroll
  for (int i = 0; i < 4; i++) {
    float inv = 1.0f / li[i];
    int p = pl + 32 * i;
    #pragma unroll
    for (int d = 0; d < 8; d++) ao[p * 65 + 8 * h + d] = acc[i][d] * inv;
  }
  __syncthreads();

  // ---- O phase: out[p][co] = ao[p] . woT[:,co] + bo ----
  int q2 = t & 127;
  int chalf = __builtin_amdgcn_readfirstlane((t >> 7) & 1);  // wave-uniform -> scalar weight loads
  float acc2[32];
  #pragma unroll
  for (int j2 = 0; j2 < 32; j2++) acc2[j2] = bo[chalf * 32 + j2];
  const float* aor = ao + q2 * 65;
  #pragma unroll 4
  for (int c = 0; c < 64; c++) {
    float xv = aor[c];
    const float* wr = woT + c * 64 + chalf * 32;
    #pragma unroll
    for (int j2 = 0; j2 < 32; j2++) acc2[j2] = fmaf(xv, wr[j2], acc2[j2]);
  }
  float* ob = out + b * (CHN * HW) + p0 + q2;
  #pragma unroll
  for (int j2 = 0; j2 < 32; j2++) ob[(chalf * 32 + j2) * HW] = acc2[j2];
}

extern "C" void kernel_launch(void* const* d_in, const int* in_sizes, int n_in,
                              void* d_out, int out_size, void* d_ws, size_t ws_size,
                              hipStream_t stream) {
  const float* z    = (const float*)d_in[0];
  const float* cond = (const float*)d_in[1];
  const float* Wq = (const float*)d_in[2];  const float* bq = (const float*)d_in[3];
  const float* Aq = (const float*)d_in[4];  const float* Bq = (const float*)d_in[5];
  const float* Wk = (const float*)d_in[6];  const float* bk = (const float*)d_in[7];
  const float* Ak = (const float*)d_in[8];  const float* Bk = (const float*)d_in[9];
  const float* Wv = (const float*)d_in[10]; const float* bv = (const float*)d_in[11];
  const float* Av = (const float*)d_in[12]; const float* Bv = (const float*)d_in[13];
  const float* Wo = (const float*)d_in[14]; const float* bo = (const float*)d_in[15];
  const float* Ao = (const float*)d_in[16]; const float* Bo = (const float*)d_in[17];
  float* ws  = (float*)d_ws;
  float* out = (float*)d_out;

  prep_weights<<<416, 256, 0, stream>>>(Wq, Aq, Bq, Wk, Ak, Bk, Wv, Av, Bv, Wo, Ao, Bo, ws);
  kvproj5<<<dim3(308, 2), 256, 0, stream>>>(cond, ws + OFF_WK, ws + OFF_WV, bk, bv,
                                            ws + OFF_K, ws + OFF_V);
  megattn<<<dim3(32, 16), 256, 0, stream>>>(z, ws + OFF_WQ, bq, ws + OFF_K, ws + OFF_V,
                                            ws + OFF_WO, bo, out);
}

// Round 15
// 147.120 us; speedup vs baseline: 1.0736x; 1.0736x over previous
//
#include <hip/hip_runtime.h>

// CrossAttention with LoRA (folded). B=16, C=64, hw=4096, L=77, COND=768, HEADS=8, dh=8.
// Round 16: megattn wq->LDS. r14 measured LDS-staged reads beat L1-hit global reads by
// ~28ns/load (308 loads <-> +9us). Q phase has 128 such loads (wqT, per-lane h) -> stage
// wqT (16KB) into LDS once per block; Q reads become conflict-free broadcasts.
// LDS 39.4->55.8KB (still 2 blocks/CU). Barriers still 3 (stage->{Q,attn} share one;
// Q and attention back-to-back). Everything else byte-identical r6.
// Pipeline: prep_weights -> kvproj5 -> megattn  (3 launches).

#define HW   4096
#define CHN  64
#define LSEQ 77
#define CD   768
#define NB   16

// workspace float offsets
#define OFF_WQ 0
#define OFF_WK 4096
#define OFF_WV 53248
#define OFF_WO 102400
#define OFF_K  106496
#define OFF_V  185344

#define QF 0.51011784563163f  // SCALE * log2(e) = 8^-0.5 * 1.442695...

__global__ __launch_bounds__(256) void prep_weights(
    const float* __restrict__ Wq, const float* __restrict__ Aq, const float* __restrict__ Bq,
    const float* __restrict__ Wk, const float* __restrict__ Ak, const float* __restrict__ Bk,
    const float* __restrict__ Wv, const float* __restrict__ Av, const float* __restrict__ Bv,
    const float* __restrict__ Wo, const float* __restrict__ Ao, const float* __restrict__ Bo,
    float* __restrict__ ws) {
  int idx = blockIdx.x * 256 + threadIdx.x;   // 416*256 = 106496 exact
  const float *W, *A, *Bm;
  float* out;
  int in_d, local;
  float scale = 1.0f;
  if (idx < 4096)        { W = Wq; A = Aq; Bm = Bq; out = ws + OFF_WQ; in_d = 64;  local = idx; scale = QF; }
  else if (idx < 53248)  { W = Wk; A = Ak; Bm = Bk; out = ws + OFF_WK; in_d = 768; local = idx - 4096; }
  else if (idx < 102400) { W = Wv; A = Av; Bm = Bv; out = ws + OFF_WV; in_d = 768; local = idx - 53248; }
  else                   { W = Wo; A = Ao; Bm = Bo; out = ws + OFF_WO; in_d = 64;  local = idx - 102400; }
  int co = local & 63;
  int c  = local >> 6;
  float val = W[co * in_d + c];
  #pragma unroll
  for (int r = 0; r < 8; r++) val += Bm[co * 8 + r] * A[r * in_d + c];
  out[local] = val * scale;   // local == c*64+co : W_eff^T [in][out]
}

// K/V projection (verified r6): grid (308, 2 kv), block 256 = 4 waves.
// Wave q owns K-quarter; lane l: l16=l&15 (co quad), cs=l>>4. Weight fetch float4:
// wave = 1KB contiguous; x reads = LDS broadcasts; 16 partial groups -> LDS reduce.
__global__ __launch_bounds__(256) void kvproj5(
    const float* __restrict__ cond,  // [1232][768]
    const float* __restrict__ wkT,   // [768][64]
    const float* __restrict__ wvT,
    const float* __restrict__ bk, const float* __restrict__ bv,
    float* __restrict__ kbuf,        // [1232][64]
    float* __restrict__ vbuf) {
  __shared__ float xs[4 * CD];       // 12KB: x[4 rows][768]
  __shared__ float red[16 * 256];    // 16KB: [group][row][co]
  int kv = blockIdx.y;
  int r0 = blockIdx.x * 4;           // 308*4 = 1232 exact
  int t  = threadIdx.x;
  int l  = t & 63;
  int q  = __builtin_amdgcn_readfirstlane(t >> 6);   // wave id = K-quarter
  int l16 = l & 15;
  int cs  = l >> 4;                  // c-phase within quarter

  {
    const float4* src = (const float4*)(cond + r0 * CD);
    float4* dst = (float4*)xs;
    #pragma unroll
    for (int i = 0; i < 3; i++) dst[t + 256 * i] = src[t + 256 * i];  // 768 float4 exact
  }
  __syncthreads();

  const float4* wT4 = (const float4*)(kv ? wvT : wkT);   // [768*16] float4
  float4 a0 = make_float4(0.f, 0.f, 0.f, 0.f);
  float4 a1 = a0, a2 = a0, a3 = a0;
  int cbase = q * 192 + cs;
  #pragma unroll 8
  for (int it = 0; it < 48; it++) {
    int c = cbase + 4 * it;
    float4 w  = wT4[c * 16 + l16];       // wave: 64 consecutive float4 = 1KB
    float x0 = xs[0 * CD + c];           // 4 distinct addrs, 16-lane broadcast each
    float x1 = xs[1 * CD + c];
    float x2 = xs[2 * CD + c];
    float x3 = xs[3 * CD + c];
    a0.x = fmaf(x0, w.x, a0.x); a0.y = fmaf(x0, w.y, a0.y);
    a0.z = fmaf(x0, w.z, a0.z); a0.w = fmaf(x0, w.w, a0.w);
    a1.x = fmaf(x1, w.x, a1.x); a1.y = fmaf(x1, w.y, a1.y);
    a1.z = fmaf(x1, w.z, a1.z); a1.w = fmaf(x1, w.w, a1.w);
    a2.x = fmaf(x2, w.x, a2.x); a2.y = fmaf(x2, w.y, a2.y);
    a2.z = fmaf(x2, w.z, a2.z); a2.w = fmaf(x2, w.w, a2.w);
    a3.x = fmaf(x3, w.x, a3.x); a3.y = fmaf(x3, w.y, a3.y);
    a3.z = fmaf(x3, w.z, a3.z); a3.w = fmaf(x3, w.w, a3.w);
  }

  {
    float4* redq = (float4*)(red + (q * 4 + cs) * 256);
    redq[0 * 16 + l16] = a0;   // row 0
    redq[1 * 16 + l16] = a1;
    redq[2 * 16 + l16] = a2;
    redq[3 * 16 + l16] = a3;
  }
  __syncthreads();

  int r  = t >> 6;                  // 4 rows x 64 co = 256 outputs exact
  int co = t & 63;
  float val = (kv ? bv : bk)[co];
  #pragma unroll
  for (int g = 0; g < 16; g++) val += red[g * 256 + r * 64 + co];
  (kv ? vbuf : kbuf)[(r0 + r) * 64 + co] = val;
}

// Fused q-proj + attention + o-proj. grid (32 ptiles of 128, 16 b), block 256.
// h = t>>5, pl = t&31, 4 px/thread. K/V AND wqT staged in LDS (55.8KB, 2 blocks/CU).
// Q phase reads wq from LDS (2 addrs/wave broadcast, conflict-free) — converts 128
// L1-hit VMEM loads to LDS reads (r14-measured ~28ns/load cheaper).
// ao reuses smem [128][65]. Barriers: stage -> {Q,attn} ; attn -> ao ; ao -> O.
__global__ __launch_bounds__(256, 2) void megattn(
    const float* __restrict__ z,     // [16][64][4096]
    const float* __restrict__ wqT,   // [64][64] (pre-scaled by QF)
    const float* __restrict__ bq,
    const float* __restrict__ kbuf,  // [16][77][64]
    const float* __restrict__ vbuf,
    const float* __restrict__ woT,   // [64][64]
    const float* __restrict__ bo,
    float* __restrict__ out) {       // [16][64][4096]
  __shared__ float smem[LSEQ * 64 * 2 + 4096];   // k|v|wq = 13952 floats (55.8KB); ao reuse
  int b  = blockIdx.y;
  int p0 = blockIdx.x * 128;
  int t  = threadIdx.x;
  int h  = t >> 5;
  int pl = t & 31;

  float* ks  = smem;
  float* vs  = smem + LSEQ * 64;
  float* wqs = smem + LSEQ * 64 * 2;
  {
    const float4* ksrc = (const float4*)(kbuf + b * LSEQ * 64);
    const float4* vsrc = (const float4*)(vbuf + b * LSEQ * 64);
    float4* kd = (float4*)ks;
    float4* vd = (float4*)vs;
    for (int i = t; i < LSEQ * 16; i += 256) { kd[i] = ksrc[i]; vd[i] = vsrc[i]; }
    const float4* wsrc = (const float4*)wqT;
    float4* wd = (float4*)wqs;
    #pragma unroll
    for (int i = 0; i < 4; i++) wd[t + 256 * i] = wsrc[t + 256 * i];   // 1024 float4 exact
  }
  __syncthreads();

  // ---- Q phase (wq from LDS): q[p][8h..8h+7] for p = p0 + pl + 32*i, i<4 ----
  float qr[4][8];
  {
    const float4 b0 = *(const float4*)(bq + 8 * h);
    const float4 b1 = *(const float4*)(bq + 8 * h + 4);
    #pragma unroll
    for (int i = 0; i < 4; i++) {
      qr[i][0] = b0.x * QF; qr[i][1] = b0.y * QF; qr[i][2] = b0.z * QF; qr[i][3] = b0.w * QF;
      qr[i][4] = b1.x * QF; qr[i][5] = b1.y * QF; qr[i][6] = b1.z * QF; qr[i][7] = b1.w * QF;
    }
  }
  const float* zb = z + b * (CHN * HW) + p0 + pl;
  #pragma unroll 4
  for (int c = 0; c < 64; c++) {
    float4 w0 = *(const float4*)(wqs + c * 64 + 8 * h);      // LDS broadcast, conflict-free
    float4 w1 = *(const float4*)(wqs + c * 64 + 8 * h + 4);
    float zv[4];
    #pragma unroll
    for (int i = 0; i < 4; i++) zv[i] = zb[c * HW + 32 * i];
    #pragma unroll
    for (int i = 0; i < 4; i++) {
      qr[i][0] = fmaf(zv[i], w0.x, qr[i][0]);
      qr[i][1] = fmaf(zv[i], w0.y, qr[i][1]);
      qr[i][2] = fmaf(zv[i], w0.z, qr[i][2]);
      qr[i][3] = fmaf(zv[i], w0.w, qr[i][3]);
      qr[i][4] = fmaf(zv[i], w1.x, qr[i][4]);
      qr[i][5] = fmaf(zv[i], w1.y, qr[i][5]);
      qr[i][6] = fmaf(zv[i], w1.z, qr[i][6]);
      qr[i][7] = fmaf(zv[i], w1.w, qr[i][7]);
    }
  }
  // no barrier: attention reads k/v (staged before the same barrier as wq)

  // ---- Attention phase ----
  float acc[4][8];
  float li[4];
  #pragma unroll
  for (int i = 0; i < 4; i++) {
    li[i] = 0.f;
    #pragma unroll
    for (int d = 0; d < 8; d++) acc[i][d] = 0.f;
  }
  #pragma unroll 2
  for (int j = 0; j < LSEQ; j++) {
    float4 k0 = *(const float4*)(ks + j * 64 + 8 * h);
    float4 k1 = *(const float4*)(ks + j * 64 + 8 * h + 4);
    float4 v0 = *(const float4*)(vs + j * 64 + 8 * h);
    float4 v1 = *(const float4*)(vs + j * 64 + 8 * h + 4);
    #pragma unroll
    for (int i = 0; i < 4; i++) {
      float s = qr[i][0] * k0.x;
      s = fmaf(qr[i][1], k0.y, s);
      s = fmaf(qr[i][2], k0.z, s);
      s = fmaf(qr[i][3], k0.w, s);
      s = fmaf(qr[i][4], k1.x, s);
      s = fmaf(qr[i][5], k1.y, s);
      s = fmaf(qr[i][6], k1.z, s);
      s = fmaf(qr[i][7], k1.w, s);
      float e = __builtin_amdgcn_exp2f(s);
      li[i] += e;
      acc[i][0] = fmaf(e, v0.x, acc[i][0]);
      acc[i][1] = fmaf(e, v0.y, acc[i][1]);
      acc[i][2] = fmaf(e, v0.z, acc[i][2]);
      acc[i][3] = fmaf(e, v0.w, acc[i][3]);
      acc[i][4] = fmaf(e, v1.x, acc[i][4]);
      acc[i][5] = fmaf(e, v1.y, acc[i][5]);
      acc[i][6] = fmaf(e, v1.z, acc[i][6]);
      acc[i][7] = fmaf(e, v1.w, acc[i][7]);
    }
  }
  __syncthreads();   // all k/v/wq reads done; smem reusable

  // ---- ao -> LDS, layout [128][65] (stride 65: 2 lanes/bank = free) ----
  float* ao = smem;
  #pragma unroll
  for (int i = 0; i < 4; i++) {
    float inv = 1.0f / li[i];
    int p = pl + 32 * i;
    #pragma unroll
    for (int d = 0; d < 8; d++) ao[p * 65 + 8 * h + d] = acc[i][d] * inv;
  }
  __syncthreads();

  // ---- O phase: out[p][co] = ao[p] . woT[:,co] + bo ----
  int q2 = t & 127;
  int chalf = __builtin_amdgcn_readfirstlane((t >> 7) & 1);  // wave-uniform -> scalar weight loads
  float acc2[32];
  #pragma unroll
  for (int j2 = 0; j2 < 32; j2++) acc2[j2] = bo[chalf * 32 + j2];
  const float* aor = ao + q2 * 65;
  #pragma unroll 4
  for (int c = 0; c < 64; c++) {
    float xv = aor[c];
    const float* wr = woT + c * 64 + chalf * 32;
    #pragma unroll
    for (int j2 = 0; j2 < 32; j2++) acc2[j2] = fmaf(xv, wr[j2], acc2[j2]);
  }
  float* ob = out + b * (CHN * HW) + p0 + q2;
  #pragma unroll
  for (int j2 = 0; j2 < 32; j2++) ob[(chalf * 32 + j2) * HW] = acc2[j2];
}

extern "C" void kernel_launch(void* const* d_in, const int* in_sizes, int n_in,
                              void* d_out, int out_size, void* d_ws, size_t ws_size,
                              hipStream_t stream) {
  const float* z    = (const float*)d_in[0];
  const float* cond = (const float*)d_in[1];
  const float* Wq = (const float*)d_in[2];  const float* bq = (const float*)d_in[3];
  const float* Aq = (const float*)d_in[4];  const float* Bq = (const float*)d_in[5];
  const float* Wk = (const float*)d_in[6];  const float* bk = (const float*)d_in[7];
  const float* Ak = (const float*)d_in[8];  const float* Bk = (const float*)d_in[9];
  const float* Wv = (const float*)d_in[10]; const float* bv = (const float*)d_in[11];
  const float* Av = (const float*)d_in[12]; const float* Bv = (const float*)d_in[13];
  const float* Wo = (const float*)d_in[14]; const float* bo = (const float*)d_in[15];
  const float* Ao = (const float*)d_in[16]; const float* Bo = (const float*)d_in[17];
  float* ws  = (float*)d_ws;
  float* out = (float*)d_out;

  prep_weights<<<416, 256, 0, stream>>>(Wq, Aq, Bq, Wk, Ak, Bk, Wv, Av, Bv, Wo, Ao, Bo, ws);
  kvproj5<<<dim3(308, 2), 256, 0, stream>>>(cond, ws + OFF_WK, ws + OFF_WV, bk, bv,
                                            ws + OFF_K, ws + OFF_V);
  megattn<<<dim3(32, 16), 256, 0, stream>>>(z, ws + OFF_WQ, bq, ws + OFF_K, ws + OFF_V,
                                            ws + OFF_WO, bo, out);
}